// Round 1
// baseline (607.748 us; speedup 1.0000x reference)
//
#include <hip/hip_runtime.h>
#include <math.h>

#define NN 32768
#define NG 256
#define DEG 8
#define HC 256
#define KTOP 64
#define EPSBN 1e-5f

// ---------------------------------------------------------------------------
// C[M,N] = act(A[M,K] @ B[K,N] + bias)  — 64x64 tile, 4x4 register blocking.
// M,N,K multiples of 64.
// ---------------------------------------------------------------------------
__global__ __launch_bounds__(256) void gemm_bias_act(
    const float* __restrict__ A, const float* __restrict__ B,
    const float* __restrict__ bias, float* __restrict__ C,
    int M, int K, int N, int act)
{
    __shared__ float Al[64][65];
    __shared__ float Bl[64][68];
    const int tx = threadIdx.x & 15;
    const int ty = threadIdx.x >> 4;
    const int row0 = blockIdx.y * 64;
    const int col0 = blockIdx.x * 64;
    float acc[4][4] = {};
    for (int kk = 0; kk < K; kk += 64) {
        #pragma unroll
        for (int i = 0; i < 16; i++) {
            int id = threadIdx.x + i * 256;
            int r = id >> 6, c = id & 63;
            Al[r][c] = A[(size_t)(row0 + r) * K + kk + c];
            Bl[r][c] = B[(size_t)(kk + r) * N + col0 + c];
        }
        __syncthreads();
        #pragma unroll 8
        for (int k = 0; k < 64; k++) {
            float a0 = Al[ty*4+0][k], a1 = Al[ty*4+1][k];
            float a2 = Al[ty*4+2][k], a3 = Al[ty*4+3][k];
            float b0 = Bl[k][tx*4+0], b1 = Bl[k][tx*4+1];
            float b2 = Bl[k][tx*4+2], b3 = Bl[k][tx*4+3];
            acc[0][0] += a0*b0; acc[0][1] += a0*b1; acc[0][2] += a0*b2; acc[0][3] += a0*b3;
            acc[1][0] += a1*b0; acc[1][1] += a1*b1; acc[1][2] += a1*b2; acc[1][3] += a1*b3;
            acc[2][0] += a2*b0; acc[2][1] += a2*b1; acc[2][2] += a2*b2; acc[2][3] += a2*b3;
            acc[3][0] += a3*b0; acc[3][1] += a3*b1; acc[3][2] += a3*b2; acc[3][3] += a3*b3;
        }
        __syncthreads();
    }
    #pragma unroll
    for (int i = 0; i < 4; i++) {
        int r = row0 + ty*4 + i;
        #pragma unroll
        for (int j = 0; j < 4; j++) {
            int c = col0 + tx*4 + j;
            float v = acc[i][j] + bias[c];
            if (act) v = fmaxf(v, 0.f);
            C[(size_t)r * N + c] = v;
        }
    }
}

// ---------------------------------------------------------------------------
// Attention + beta gate. One 64-lane wave per node (4 nodes/block).
// dst[e] == e/8 by construction. Edge embedding recomputed from LDS-cached We.
// H may alias Q (Q[n] only read by node n's own wave, before the write).
// ---------------------------------------------------------------------------
__global__ __launch_bounds__(256) void attn_beta(
    const float* __restrict__ Q, const float* __restrict__ Kf,
    const float* __restrict__ Vf, const float* __restrict__ S,
    const float* __restrict__ We, const float* __restrict__ Wb,
    const int* __restrict__ srcIdx, const float* __restrict__ EA,
    float* __restrict__ H)
{
    __shared__ float WeL[16 * 256];
    for (int i = threadIdx.x; i < 16 * 256; i += 256) WeL[i] = We[i];
    __syncthreads();
    const int lane = threadIdx.x & 63;
    const int wave = threadIdx.x >> 6;
    const int n = blockIdx.x * 4 + wave;
    const int c0 = lane * 4;
    const float4* WeL4 = (const float4*)WeL;
    float4 q = *(const float4*)(Q + (size_t)n * HC + c0);
    float4 ve[DEG];
    float alpha[DEG];
    #pragma unroll
    for (int j = 0; j < DEG; j++) {
        int e = n * DEG + j;
        int s = srcIdx[e];
        float eav = EA[(size_t)e * 16 + (lane & 15)];
        float eex = 0.f, eey = 0.f, eez = 0.f, eew = 0.f;
        #pragma unroll
        for (int f = 0; f < 16; f++) {
            float a = __shfl(eav, f, 16);
            float4 w = WeL4[f * 64 + lane];
            eex += a * w.x; eey += a * w.y; eez += a * w.z; eew += a * w.w;
        }
        float4 kv = *(const float4*)(Kf + (size_t)s * HC + c0);
        float4 vv = *(const float4*)(Vf + (size_t)s * HC + c0);
        float kx = kv.x + eex, ky = kv.y + eey, kz = kv.z + eez, kw = kv.w + eew;
        ve[j].x = vv.x + eex; ve[j].y = vv.y + eey;
        ve[j].z = vv.z + eez; ve[j].w = vv.w + eew;
        float d = q.x*kx + q.y*ky + q.z*kz + q.w*kw;
        d += __shfl_xor(d, 1); d += __shfl_xor(d, 2);
        d += __shfl_xor(d, 4); d += __shfl_xor(d, 8);
        alpha[j] = d * 0.125f;   // 1/sqrt(64)
    }
    float mx = alpha[0];
    #pragma unroll
    for (int j = 1; j < DEG; j++) mx = fmaxf(mx, alpha[j]);
    float wsum = 0.f;
    float wgt[DEG];
    #pragma unroll
    for (int j = 0; j < DEG; j++) { wgt[j] = expf(alpha[j] - mx); wsum += wgt[j]; }
    float inv = 1.f / wsum;
    float ox = 0.f, oy = 0.f, oz = 0.f, ow = 0.f;
    #pragma unroll
    for (int j = 0; j < DEG; j++) {
        float wj = wgt[j] * inv;
        ox += wj*ve[j].x; oy += wj*ve[j].y; oz += wj*ve[j].z; ow += wj*ve[j].w;
    }
    float4 xr = *(const float4*)(S + (size_t)n * HC + c0);
    float part = ox*Wb[c0+0] + oy*Wb[c0+1] + oz*Wb[c0+2] + ow*Wb[c0+3]
               + xr.x*Wb[256+c0+0] + xr.y*Wb[256+c0+1]
               + xr.z*Wb[256+c0+2] + xr.w*Wb[256+c0+3]
               + (ox-xr.x)*Wb[512+c0+0] + (oy-xr.y)*Wb[512+c0+1]
               + (oz-xr.z)*Wb[512+c0+2] + (ow-xr.w)*Wb[512+c0+3];
    part += __shfl_xor(part, 1);  part += __shfl_xor(part, 2);
    part += __shfl_xor(part, 4);  part += __shfl_xor(part, 8);
    part += __shfl_xor(part, 16); part += __shfl_xor(part, 32);
    float beta = 1.f / (1.f + expf(-part));
    float4 h;
    h.x = beta*xr.x + (1.f-beta)*ox;
    h.y = beta*xr.y + (1.f-beta)*oy;
    h.z = beta*xr.z + (1.f-beta)*oz;
    h.w = beta*xr.w + (1.f-beta)*ow;
    *(float4*)(H + (size_t)n * HC + c0) = h;
}

// ---------------------------------------------------------------------------
// BatchNorm helpers: stats (sum, sumsq per column) then normalize in place.
// ---------------------------------------------------------------------------
__global__ void zero_stats(float* __restrict__ s) { s[threadIdx.x] = 0.f; }

__global__ __launch_bounds__(256) void bn_stats(
    const float* __restrict__ T, float* __restrict__ stats)
{
    const int c = threadIdx.x & 63;
    const int rg = threadIdx.x >> 6;
    float s = 0.f, s2 = 0.f;
    for (int r = blockIdx.x * 4 + rg; r < NN; r += gridDim.x * 4) {
        float v = T[(size_t)r * 64 + c];
        s += v; s2 += v * v;
    }
    __shared__ float red[256], red2[256];
    red[threadIdx.x] = s; red2[threadIdx.x] = s2;
    __syncthreads();
    if (threadIdx.x < 64) {
        s  = red[c]  + red[64+c]  + red[128+c]  + red[192+c];
        s2 = red2[c] + red2[64+c] + red2[128+c] + red2[192+c];
        atomicAdd(&stats[c], s);
        atomicAdd(&stats[64 + c], s2);
    }
}

__global__ __launch_bounds__(256) void bn_apply(
    float* __restrict__ T, const float* __restrict__ stats,
    const float* __restrict__ g, const float* __restrict__ b)
{
    int i = blockIdx.x * 256 + threadIdx.x;
    int c = i & 63;
    float mean = stats[c] * (1.f / NN);
    float var  = stats[64 + c] * (1.f / NN) - mean * mean;
    float v = T[i];
    T[i] = g[c] * (v - mean) * rsqrtf(var + EPSBN) + b[c];
}

// ---------------------------------------------------------------------------
// TopK pooling + readout + MLP head. One block (128 threads) per graph.
// ---------------------------------------------------------------------------
__global__ __launch_bounds__(128) void pool_mlp(
    const float* __restrict__ Hn, const float* __restrict__ pw,
    const float* __restrict__ W1, const float* __restrict__ b1,
    const float* __restrict__ W2, const float* __restrict__ b2,
    const float* __restrict__ W3, const float* __restrict__ b3,
    float* __restrict__ out)
{
    __shared__ float sh[128][65];
    __shared__ float spw[64];
    __shared__ float sc[128];
    __shared__ float sscale[128];
    __shared__ int   skeep[128];
    __shared__ float rmax[2][64], rsum[2][64];
    __shared__ float srep[128];
    __shared__ float sh1[256];
    __shared__ float sh2[128];
    __shared__ float wred[2];
    const int g = blockIdx.x, t = threadIdx.x;

    for (int i = t; i < 128 * 64; i += 128) sh[i >> 6][i & 63] = Hn[(size_t)g * 128 * 64 + i];
    if (t < 64) spw[t] = pw[t];
    __syncthreads();

    float nw = 0.f;
    #pragma unroll
    for (int i = 0; i < 64; i++) { float w = spw[i]; nw += w * w; }
    float invn = rsqrtf(nw);

    float s = 0.f;
    #pragma unroll
    for (int i = 0; i < 64; i++) s += sh[t][i] * spw[i];
    s *= invn;
    sc[t] = s;
    __syncthreads();

    int rank = 0;
    for (int m = 0; m < 128; m++) {
        float sm = sc[m];
        rank += (sm > s) || (sm == s && m < t);
    }
    skeep[t] = (rank < KTOP);
    sscale[t] = tanhf(s);
    __syncthreads();

    {
        int c = t & 63, half = t >> 6;
        float mxv = -1e30f, sm = 0.f;
        for (int r = half * 64; r < half * 64 + 64; r++) {
            if (skeep[r]) {
                float v = sh[r][c] * sscale[r];
                mxv = fmaxf(mxv, v); sm += v;
            }
        }
        rmax[half][c] = mxv; rsum[half][c] = sm;
    }
    __syncthreads();
    if (t < 64) {
        srep[t] = fmaxf(rmax[0][t], rmax[1][t]);
        srep[64 + t] = (rsum[0][t] + rsum[1][t]) * (1.f / KTOP);
    }
    __syncthreads();

    #pragma unroll
    for (int jj = 0; jj < 2; jj++) {
        int j = t + jj * 128;
        float a = b1[j];
        for (int c2 = 0; c2 < 128; c2++) a += srep[c2] * W1[c2 * 256 + j];
        sh1[j] = fmaxf(a, 0.f);
    }
    __syncthreads();
    {
        float a = b2[t];
        for (int c2 = 0; c2 < 256; c2++) a += sh1[c2] * W2[c2 * 128 + t];
        sh2[t] = fmaxf(a, 0.f);
    }
    __syncthreads();
    float p = sh2[t] * W3[t];
    p += __shfl_xor(p, 1);  p += __shfl_xor(p, 2);  p += __shfl_xor(p, 4);
    p += __shfl_xor(p, 8);  p += __shfl_xor(p, 16); p += __shfl_xor(p, 32);
    if ((t & 63) == 0) wred[t >> 6] = p;
    __syncthreads();
    if (t == 0) out[g] = wred[0] + wred[1] + b3[0];
}

// ---------------------------------------------------------------------------
extern "C" void kernel_launch(void* const* d_in, const int* in_sizes, int n_in,
                              void* d_out, int out_size, void* d_ws, size_t ws_size,
                              hipStream_t stream)
{
    const float* x    = (const float*)d_in[0];
    const int*   ei   = (const int*)  d_in[1];
    const float* ea   = (const float*)d_in[2];
    const int*   srcI = ei;  // row 0 of edge_index
    const float* Wq1 = (const float*)d_in[4];  const float* bq1 = (const float*)d_in[5];
    const float* Wk1 = (const float*)d_in[6];  const float* bk1 = (const float*)d_in[7];
    const float* Wv1 = (const float*)d_in[8];  const float* bv1 = (const float*)d_in[9];
    const float* We1 = (const float*)d_in[10];
    const float* Ws1 = (const float*)d_in[11]; const float* bs1 = (const float*)d_in[12];
    const float* Wb1 = (const float*)d_in[13];
    const float* t1W = (const float*)d_in[14]; const float* t1b = (const float*)d_in[15];
    const float* g1  = (const float*)d_in[16]; const float* be1 = (const float*)d_in[17];
    const float* Wq2 = (const float*)d_in[18]; const float* bq2 = (const float*)d_in[19];
    const float* Wk2 = (const float*)d_in[20]; const float* bk2 = (const float*)d_in[21];
    const float* Wv2 = (const float*)d_in[22]; const float* bv2 = (const float*)d_in[23];
    const float* We2 = (const float*)d_in[24];
    const float* Ws2 = (const float*)d_in[25]; const float* bs2 = (const float*)d_in[26];
    const float* Wb2 = (const float*)d_in[27];
    const float* t2W = (const float*)d_in[28]; const float* t2b = (const float*)d_in[29];
    const float* g2  = (const float*)d_in[30]; const float* be2 = (const float*)d_in[31];
    const float* pw  = (const float*)d_in[32];
    const float* l1W = (const float*)d_in[33]; const float* l1b = (const float*)d_in[34];
    const float* l2W = (const float*)d_in[35]; const float* l2b = (const float*)d_in[36];
    const float* l3W = (const float*)d_in[37]; const float* l3b = (const float*)d_in[38];

    float* bQ = (float*)d_ws;                  // [NN,256] — also attn output h
    float* bK = bQ + (size_t)NN * HC;          // [NN,256]
    float* bV = bK + (size_t)NN * HC;          // [NN,256]
    float* bS = bV + (size_t)NN * HC;          // [NN,256]
    float* bT = bS + (size_t)NN * HC;          // [NN,64]
    float* stats = bT + (size_t)NN * 64;       // [128]
    float* bT2 = bK;                           // alias: bK dead by then

    const dim3 blk(256);
    const dim3 gProj(4, 512);   // N=256 cols, M=32768 rows
    const dim3 gT(1, 512);      // N=64

    // ---- layer 1 ----
    gemm_bias_act<<<gProj, blk, 0, stream>>>(x, Wq1, bq1, bQ, NN, 64, 256, 0);
    gemm_bias_act<<<gProj, blk, 0, stream>>>(x, Wk1, bk1, bK, NN, 64, 256, 0);
    gemm_bias_act<<<gProj, blk, 0, stream>>>(x, Wv1, bv1, bV, NN, 64, 256, 0);
    gemm_bias_act<<<gProj, blk, 0, stream>>>(x, Ws1, bs1, bS, NN, 64, 256, 0);
    attn_beta<<<NN / 4, blk, 0, stream>>>(bQ, bK, bV, bS, We1, Wb1, srcI, ea, bQ);
    gemm_bias_act<<<gT, blk, 0, stream>>>(bQ, t1W, t1b, bT, NN, 256, 64, 1);
    zero_stats<<<1, 128, 0, stream>>>(stats);
    bn_stats<<<256, blk, 0, stream>>>(bT, stats);
    bn_apply<<<NN * 64 / 256, blk, 0, stream>>>(bT, stats, g1, be1);

    // ---- layer 2 ----
    gemm_bias_act<<<gProj, blk, 0, stream>>>(bT, Wq2, bq2, bQ, NN, 64, 256, 0);
    gemm_bias_act<<<gProj, blk, 0, stream>>>(bT, Wk2, bk2, bK, NN, 64, 256, 0);
    gemm_bias_act<<<gProj, blk, 0, stream>>>(bT, Wv2, bv2, bV, NN, 64, 256, 0);
    gemm_bias_act<<<gProj, blk, 0, stream>>>(bT, Ws2, bs2, bS, NN, 64, 256, 0);
    attn_beta<<<NN / 4, blk, 0, stream>>>(bQ, bK, bV, bS, We2, Wb2, srcI, ea, bQ);
    gemm_bias_act<<<gT, blk, 0, stream>>>(bQ, t2W, t2b, bT2, NN, 256, 64, 1);
    zero_stats<<<1, 128, 0, stream>>>(stats);
    bn_stats<<<256, blk, 0, stream>>>(bT2, stats);
    bn_apply<<<NN * 64 / 256, blk, 0, stream>>>(bT2, stats, g2, be2);

    // ---- pooling + head ----
    pool_mlp<<<NG, 128, 0, stream>>>(bT2, pw, l1W, l1b, l2W, l2b, l3W, l3b,
                                     (float*)d_out);
}

// Round 2
// 421.110 us; speedup vs baseline: 1.4432x; 1.4432x over previous
//
#include <hip/hip_runtime.h>
#include <math.h>

#define NN 32768
#define NG 256
#define DEG 8
#define HC 256
#define NCAT 1088          // Q(256)|K(256)|V(256)|S(768..1023)|QE(1024..1087)
#define KTOP 64
#define EPSBN 1e-5f

// ---------------- bf16 helpers ----------------
__device__ inline float bf2f(unsigned short u) {
    union { unsigned int i; float f; } c; c.i = ((unsigned int)u) << 16; return c.f;
}
__device__ inline unsigned short f2bf(float f) {
    union { float f; unsigned int i; } c; c.f = f;
    unsigned int r = c.i + 0x7FFFu + ((c.i >> 16) & 1u);
    return (unsigned short)(r >> 16);
}
__device__ inline float4 load4bf(const unsigned short* p) {
    ushort4 u = *(const ushort4*)p;
    float4 r; r.x = bf2f(u.x); r.y = bf2f(u.y); r.z = bf2f(u.z); r.w = bf2f(u.w);
    return r;
}

// ---------------------------------------------------------------------------
// Build concatenated projection weights Wcat[64][1088] + bcat[1088]:
//   cols 0..255 Wq | 256..511 Wk | 512..767 Wv | 768..1023 Ws |
//   1024..1087 Wqe where Wqe[i][h*16+f] = sum_d Wq[i][h*64+d]*We[f][h*64+d]
// ---------------------------------------------------------------------------
__global__ __launch_bounds__(256) void prep_wcat(
    const float* __restrict__ Wq, const float* __restrict__ bq,
    const float* __restrict__ Wk, const float* __restrict__ bk,
    const float* __restrict__ Wv, const float* __restrict__ bv,
    const float* __restrict__ Ws, const float* __restrict__ bs,
    const float* __restrict__ We,
    float* __restrict__ Wcat, float* __restrict__ bcat)
{
    const int t = threadIdx.x;
    if (blockIdx.x < 16) {
        int base = blockIdx.x * 4096;
        #pragma unroll
        for (int k = 0; k < 16; k++) {
            int idx = base + k * 256 + t;         // 0..65535 over [64][1024]
            int i = idx >> 10, c = idx & 1023;
            const float* src;
            int cc = c & 255;
            if (c < 256)      src = Wq;
            else if (c < 512) src = Wk;
            else if (c < 768) src = Wv;
            else              src = Ws;
            Wcat[i * NCAT + c] = src[i * 256 + cc];
        }
        if (blockIdx.x == 0) {
            for (int c = t; c < 1024; c += 256) {
                int cc = c & 255;
                float v;
                if (c < 256)      v = bq[cc];
                else if (c < 512) v = bk[cc];
                else if (c < 768) v = bv[cc];
                else              v = bs[cc];
                bcat[c] = v;
            }
        }
    } else {
        // qe weights
        int o = t & 63, seg = t >> 6;
        int h = o >> 4, f = o & 15;
        for (int i = seg * 16; i < seg * 16 + 16; i++) {
            float s = 0.f;
            #pragma unroll
            for (int d = 0; d < 64; d++)
                s += Wq[i * 256 + h * 64 + d] * We[f * 256 + h * 64 + d];
            Wcat[i * NCAT + 1024 + o] = s;
        }
        if (seg == 0) {
            float s = 0.f;
            #pragma unroll
            for (int d = 0; d < 64; d++)
                s += bq[h * 64 + d] * We[f * 256 + h * 64 + d];
            bcat[1024 + o] = s;
        }
    }
}

// ---------------------------------------------------------------------------
// Fused projection: C_bf16[M,1088] = A[M,64] @ Wcat[64,1088] + bcat
// 64x64 tile, single K stage (K=64), 4x4 register blocking.
// ---------------------------------------------------------------------------
__global__ __launch_bounds__(256) void proj_gemm(
    const float* __restrict__ A, const float* __restrict__ Wcat,
    const float* __restrict__ bcat, unsigned short* __restrict__ C)
{
    __shared__ float Al[64][65];
    __shared__ float Bl[64][68];
    const int tx = threadIdx.x & 15;
    const int ty = threadIdx.x >> 4;
    const int row0 = blockIdx.y * 64;
    const int col0 = blockIdx.x * 64;
    #pragma unroll
    for (int i = 0; i < 16; i++) {
        int id = threadIdx.x + i * 256;
        int r = id >> 6, c = id & 63;
        Al[r][c] = A[(size_t)(row0 + r) * 64 + c];
        Bl[r][c] = Wcat[r * NCAT + col0 + c];
    }
    __syncthreads();
    float acc[4][4] = {};
    #pragma unroll 8
    for (int k = 0; k < 64; k++) {
        float a0 = Al[ty*4+0][k], a1 = Al[ty*4+1][k];
        float a2 = Al[ty*4+2][k], a3 = Al[ty*4+3][k];
        float b0 = Bl[k][tx*4+0], b1 = Bl[k][tx*4+1];
        float b2 = Bl[k][tx*4+2], b3 = Bl[k][tx*4+3];
        acc[0][0] += a0*b0; acc[0][1] += a0*b1; acc[0][2] += a0*b2; acc[0][3] += a0*b3;
        acc[1][0] += a1*b0; acc[1][1] += a1*b1; acc[1][2] += a1*b2; acc[1][3] += a1*b3;
        acc[2][0] += a2*b0; acc[2][1] += a2*b1; acc[2][2] += a2*b2; acc[2][3] += a2*b3;
        acc[3][0] += a3*b0; acc[3][1] += a3*b1; acc[3][2] += a3*b2; acc[3][3] += a3*b3;
    }
    float bb[4];
    #pragma unroll
    for (int j = 0; j < 4; j++) bb[j] = bcat[col0 + tx*4 + j];
    #pragma unroll
    for (int i = 0; i < 4; i++) {
        int r = row0 + ty*4 + i;
        ushort4 pk;
        pk.x = f2bf(acc[i][0] + bb[0]);
        pk.y = f2bf(acc[i][1] + bb[1]);
        pk.z = f2bf(acc[i][2] + bb[2]);
        pk.w = f2bf(acc[i][3] + bb[3]);
        *(ushort4*)(C + (size_t)r * NCAT + col0 + tx*4) = pk;
    }
}

// ---------------------------------------------------------------------------
// Factored attention + beta gate. One 64-lane wave per node.
// Row layout in C: [Q 0..255 | K 256..511 | V 512..767 | S 768..1023 | QE 1024..1087]
// alpha_e = (q.k_src + ea_e . qe)/8 ; out = sum attn*v + (sum attn*ea) @ We
// ---------------------------------------------------------------------------
__global__ __launch_bounds__(256) void attn_fused(
    const unsigned short* __restrict__ C,
    const float* __restrict__ We, const float* __restrict__ Wb,
    const int* __restrict__ srcIdx, const float* __restrict__ EA,
    float* __restrict__ H)
{
    __shared__ float WeL[16 * 256];
    for (int i = threadIdx.x; i < 16 * 256; i += 256) WeL[i] = We[i];
    __syncthreads();
    const int lane = threadIdx.x & 63;
    const int wave = threadIdx.x >> 6;
    const int bid = blockIdx.x;
    const int swz = (bid & 7) * 1024 + (bid >> 3);   // XCD-contiguous chunks
    const int n = swz * 4 + wave;
    const int fl = lane & 15;
    const int c0 = lane * 4;

    const unsigned short* rowN = C + (size_t)n * NCAT;
    float4 q = load4bf(rowN + c0);
    float qe_l = bf2f(rowN[1024 + (lane >> 4) * 16 + fl]);

    float4 v4[DEG];
    float eas[DEG], alpha[DEG];
    const int ebase = n * DEG;
    #pragma unroll
    for (int j = 0; j < DEG; j++) {
        int s = srcIdx[ebase + j];
        const unsigned short* rowS = C + (size_t)s * NCAT;
        float4 k4 = load4bf(rowS + 256 + c0);
        v4[j] = load4bf(rowS + 512 + c0);
        eas[j] = EA[(size_t)(ebase + j) * 16 + fl];
        float d = q.x*k4.x + q.y*k4.y + q.z*k4.z + q.w*k4.w + eas[j] * qe_l;
        d += __shfl_xor(d, 1); d += __shfl_xor(d, 2);
        d += __shfl_xor(d, 4); d += __shfl_xor(d, 8);
        alpha[j] = d * 0.125f;     // 1/sqrt(64)
    }
    float mx = alpha[0];
    #pragma unroll
    for (int j = 1; j < DEG; j++) mx = fmaxf(mx, alpha[j]);
    float wsum = 0.f, wgt[DEG];
    #pragma unroll
    for (int j = 0; j < DEG; j++) { wgt[j] = expf(alpha[j] - mx); wsum += wgt[j]; }
    float inv = 1.f / wsum;

    float eagg = 0.f;
    float ox = 0.f, oy = 0.f, oz = 0.f, ow = 0.f;
    #pragma unroll
    for (int j = 0; j < DEG; j++) {
        float wj = wgt[j] * inv;
        eagg += wj * eas[j];
        ox += wj*v4[j].x; oy += wj*v4[j].y; oz += wj*v4[j].z; ow += wj*v4[j].w;
    }
    const float4* WeL4 = (const float4*)WeL;
    #pragma unroll
    for (int f = 0; f < 16; f++) {
        float a = __shfl(eagg, f, 16);
        float4 w = WeL4[f * 64 + lane];
        ox += a * w.x; oy += a * w.y; oz += a * w.z; ow += a * w.w;
    }

    float4 xr = load4bf(rowN + 768 + c0);
    float part = ox*Wb[c0+0] + oy*Wb[c0+1] + oz*Wb[c0+2] + ow*Wb[c0+3]
               + xr.x*Wb[256+c0+0] + xr.y*Wb[256+c0+1]
               + xr.z*Wb[256+c0+2] + xr.w*Wb[256+c0+3]
               + (ox-xr.x)*Wb[512+c0+0] + (oy-xr.y)*Wb[512+c0+1]
               + (oz-xr.z)*Wb[512+c0+2] + (ow-xr.w)*Wb[512+c0+3];
    part += __shfl_xor(part, 1);  part += __shfl_xor(part, 2);
    part += __shfl_xor(part, 4);  part += __shfl_xor(part, 8);
    part += __shfl_xor(part, 16); part += __shfl_xor(part, 32);
    float beta = 1.f / (1.f + expf(-part));
    float4 h;
    h.x = beta*xr.x + (1.f-beta)*ox;
    h.y = beta*xr.y + (1.f-beta)*oy;
    h.z = beta*xr.z + (1.f-beta)*oz;
    h.w = beta*xr.w + (1.f-beta)*ow;
    *(float4*)(H + (size_t)n * HC + c0) = h;
}

// ---------------------------------------------------------------------------
// Generic fp32 GEMM with bias+optional ReLU (used for the transform step).
// ---------------------------------------------------------------------------
__global__ __launch_bounds__(256) void gemm_bias_act(
    const float* __restrict__ A, const float* __restrict__ B,
    const float* __restrict__ bias, float* __restrict__ C,
    int M, int K, int N, int act)
{
    __shared__ float Al[64][65];
    __shared__ float Bl[64][68];
    const int tx = threadIdx.x & 15;
    const int ty = threadIdx.x >> 4;
    const int row0 = blockIdx.y * 64;
    const int col0 = blockIdx.x * 64;
    float acc[4][4] = {};
    for (int kk = 0; kk < K; kk += 64) {
        #pragma unroll
        for (int i = 0; i < 16; i++) {
            int id = threadIdx.x + i * 256;
            int r = id >> 6, c = id & 63;
            Al[r][c] = A[(size_t)(row0 + r) * K + kk + c];
            Bl[r][c] = B[(size_t)(kk + r) * N + col0 + c];
        }
        __syncthreads();
        #pragma unroll 8
        for (int k = 0; k < 64; k++) {
            float a0 = Al[ty*4+0][k], a1 = Al[ty*4+1][k];
            float a2 = Al[ty*4+2][k], a3 = Al[ty*4+3][k];
            float b0 = Bl[k][tx*4+0], b1 = Bl[k][tx*4+1];
            float b2 = Bl[k][tx*4+2], b3 = Bl[k][tx*4+3];
            acc[0][0] += a0*b0; acc[0][1] += a0*b1; acc[0][2] += a0*b2; acc[0][3] += a0*b3;
            acc[1][0] += a1*b0; acc[1][1] += a1*b1; acc[1][2] += a1*b2; acc[1][3] += a1*b3;
            acc[2][0] += a2*b0; acc[2][1] += a2*b1; acc[2][2] += a2*b2; acc[2][3] += a2*b3;
            acc[3][0] += a3*b0; acc[3][1] += a3*b1; acc[3][2] += a3*b2; acc[3][3] += a3*b3;
        }
        __syncthreads();
    }
    #pragma unroll
    for (int i = 0; i < 4; i++) {
        int r = row0 + ty*4 + i;
        #pragma unroll
        for (int j = 0; j < 4; j++) {
            int c = col0 + tx*4 + j;
            float v = acc[i][j] + bias[c];
            if (act) v = fmaxf(v, 0.f);
            C[(size_t)r * N + c] = v;
        }
    }
}

// ---------------------------------------------------------------------------
// BatchNorm helpers
// ---------------------------------------------------------------------------
__global__ void zero_stats(float* __restrict__ s) { s[threadIdx.x] = 0.f; }

__global__ __launch_bounds__(256) void bn_stats(
    const float* __restrict__ T, float* __restrict__ stats)
{
    const int c = threadIdx.x & 63;
    const int rg = threadIdx.x >> 6;
    float s = 0.f, s2 = 0.f;
    for (int r = blockIdx.x * 4 + rg; r < NN; r += gridDim.x * 4) {
        float v = T[(size_t)r * 64 + c];
        s += v; s2 += v * v;
    }
    __shared__ float red[256], red2[256];
    red[threadIdx.x] = s; red2[threadIdx.x] = s2;
    __syncthreads();
    if (threadIdx.x < 64) {
        s  = red[c]  + red[64+c]  + red[128+c]  + red[192+c];
        s2 = red2[c] + red2[64+c] + red2[128+c] + red2[192+c];
        atomicAdd(&stats[c], s);
        atomicAdd(&stats[64 + c], s2);
    }
}

__global__ __launch_bounds__(256) void bn_apply(
    float* __restrict__ T, const float* __restrict__ stats,
    const float* __restrict__ g, const float* __restrict__ b)
{
    int i = blockIdx.x * 256 + threadIdx.x;
    int c = i & 63;
    float mean = stats[c] * (1.f / NN);
    float var  = stats[64 + c] * (1.f / NN) - mean * mean;
    float v = T[i];
    T[i] = g[c] * (v - mean) * rsqrtf(var + EPSBN) + b[c];
}

// ---------------------------------------------------------------------------
// TopK pooling + readout + MLP head. One block (128 threads) per graph.
// ---------------------------------------------------------------------------
__global__ __launch_bounds__(128) void pool_mlp(
    const float* __restrict__ Hn, const float* __restrict__ pw,
    const float* __restrict__ W1, const float* __restrict__ b1,
    const float* __restrict__ W2, const float* __restrict__ b2,
    const float* __restrict__ W3, const float* __restrict__ b3,
    float* __restrict__ out)
{
    __shared__ float sh[128][65];
    __shared__ float spw[64];
    __shared__ float sc[128];
    __shared__ float sscale[128];
    __shared__ int   skeep[128];
    __shared__ float rmax[2][64], rsum[2][64];
    __shared__ float srep[128];
    __shared__ float sh1[256];
    __shared__ float sh2[128];
    __shared__ float wred[2];
    const int g = blockIdx.x, t = threadIdx.x;

    for (int i = t; i < 128 * 64; i += 128) sh[i >> 6][i & 63] = Hn[(size_t)g * 128 * 64 + i];
    if (t < 64) spw[t] = pw[t];
    __syncthreads();

    float nw = 0.f;
    #pragma unroll
    for (int i = 0; i < 64; i++) { float w = spw[i]; nw += w * w; }
    float invn = rsqrtf(nw);

    float s = 0.f;
    #pragma unroll
    for (int i = 0; i < 64; i++) s += sh[t][i] * spw[i];
    s *= invn;
    sc[t] = s;
    __syncthreads();

    int rank = 0;
    for (int m = 0; m < 128; m++) {
        float sm = sc[m];
        rank += (sm > s) || (sm == s && m < t);
    }
    skeep[t] = (rank < KTOP);
    sscale[t] = tanhf(s);
    __syncthreads();

    {
        int c = t & 63, half = t >> 6;
        float mxv = -1e30f, sm = 0.f;
        for (int r = half * 64; r < half * 64 + 64; r++) {
            if (skeep[r]) {
                float v = sh[r][c] * sscale[r];
                mxv = fmaxf(mxv, v); sm += v;
            }
        }
        rmax[half][c] = mxv; rsum[half][c] = sm;
    }
    __syncthreads();
    if (t < 64) {
        srep[t] = fmaxf(rmax[0][t], rmax[1][t]);
        srep[64 + t] = (rsum[0][t] + rsum[1][t]) * (1.f / KTOP);
    }
    __syncthreads();

    #pragma unroll
    for (int jj = 0; jj < 2; jj++) {
        int j = t + jj * 128;
        float a = b1[j];
        for (int c2 = 0; c2 < 128; c2++) a += srep[c2] * W1[c2 * 256 + j];
        sh1[j] = fmaxf(a, 0.f);
    }
    __syncthreads();
    {
        float a = b2[t];
        for (int c2 = 0; c2 < 256; c2++) a += sh1[c2] * W2[c2 * 128 + t];
        sh2[t] = fmaxf(a, 0.f);
    }
    __syncthreads();
    float p = sh2[t] * W3[t];
    p += __shfl_xor(p, 1);  p += __shfl_xor(p, 2);  p += __shfl_xor(p, 4);
    p += __shfl_xor(p, 8);  p += __shfl_xor(p, 16); p += __shfl_xor(p, 32);
    if ((t & 63) == 0) wred[t >> 6] = p;
    __syncthreads();
    if (t == 0) out[g] = wred[0] + wred[1] + b3[0];
}

// ---------------------------------------------------------------------------
extern "C" void kernel_launch(void* const* d_in, const int* in_sizes, int n_in,
                              void* d_out, int out_size, void* d_ws, size_t ws_size,
                              hipStream_t stream)
{
    const float* x    = (const float*)d_in[0];
    const int*   ei   = (const int*)  d_in[1];
    const float* ea   = (const float*)d_in[2];
    const int*   srcI = ei;  // row 0 of edge_index
    const float* Wq1 = (const float*)d_in[4];  const float* bq1 = (const float*)d_in[5];
    const float* Wk1 = (const float*)d_in[6];  const float* bk1 = (const float*)d_in[7];
    const float* Wv1 = (const float*)d_in[8];  const float* bv1 = (const float*)d_in[9];
    const float* We1 = (const float*)d_in[10];
    const float* Ws1 = (const float*)d_in[11]; const float* bs1 = (const float*)d_in[12];
    const float* Wb1 = (const float*)d_in[13];
    const float* t1W = (const float*)d_in[14]; const float* t1b = (const float*)d_in[15];
    const float* g1  = (const float*)d_in[16]; const float* be1 = (const float*)d_in[17];
    const float* Wq2 = (const float*)d_in[18]; const float* bq2 = (const float*)d_in[19];
    const float* Wk2 = (const float*)d_in[20]; const float* bk2 = (const float*)d_in[21];
    const float* Wv2 = (const float*)d_in[22]; const float* bv2 = (const float*)d_in[23];
    const float* We2 = (const float*)d_in[24];
    const float* Ws2 = (const float*)d_in[25]; const float* bs2 = (const float*)d_in[26];
    const float* Wb2 = (const float*)d_in[27];
    const float* t2W = (const float*)d_in[28]; const float* t2b = (const float*)d_in[29];
    const float* g2  = (const float*)d_in[30]; const float* be2 = (const float*)d_in[31];
    const float* pw  = (const float*)d_in[32];
    const float* l1W = (const float*)d_in[33]; const float* l1b = (const float*)d_in[34];
    const float* l2W = (const float*)d_in[35]; const float* l2b = (const float*)d_in[36];
    const float* l3W = (const float*)d_in[37]; const float* l3b = (const float*)d_in[38];

    char* ws = (char*)d_ws;
    unsigned short* C = (unsigned short*)ws;                 // [NN,1088] bf16
    float* H     = (float*)(ws + (size_t)NN * NCAT * 2);     // [NN,256]
    float* bT    = H + (size_t)NN * HC;                      // [NN,64]
    float* Wcat  = bT + (size_t)NN * 64;                     // [64,1088]
    float* bcat  = Wcat + 64 * NCAT;                         // [1088]
    float* stats = bcat + NCAT;                              // [128]

    const dim3 blk(256);
    const dim3 gProj(17, 512);
    const dim3 gT(1, 512);

    // ---- layer 1 ----
    prep_wcat<<<17, blk, 0, stream>>>(Wq1, bq1, Wk1, bk1, Wv1, bv1, Ws1, bs1, We1, Wcat, bcat);
    proj_gemm<<<gProj, blk, 0, stream>>>(x, Wcat, bcat, C);
    attn_fused<<<NN / 4, blk, 0, stream>>>(C, We1, Wb1, srcI, ea, H);
    gemm_bias_act<<<gT, blk, 0, stream>>>(H, t1W, t1b, bT, NN, 256, 64, 1);
    zero_stats<<<1, 128, 0, stream>>>(stats);
    bn_stats<<<256, blk, 0, stream>>>(bT, stats);
    bn_apply<<<NN * 64 / 256, blk, 0, stream>>>(bT, stats, g1, be1);

    // ---- layer 2 ----
    prep_wcat<<<17, blk, 0, stream>>>(Wq2, bq2, Wk2, bk2, Wv2, bv2, Ws2, bs2, We2, Wcat, bcat);
    proj_gemm<<<gProj, blk, 0, stream>>>(bT, Wcat, bcat, C);
    attn_fused<<<NN / 4, blk, 0, stream>>>(C, We2, Wb2, srcI, ea, H);
    gemm_bias_act<<<gT, blk, 0, stream>>>(H, t2W, t2b, bT, NN, 256, 64, 1);
    zero_stats<<<1, 128, 0, stream>>>(stats);
    bn_stats<<<256, blk, 0, stream>>>(bT, stats);
    bn_apply<<<NN * 64 / 256, blk, 0, stream>>>(bT, stats, g2, be2);

    // ---- pooling + head ----
    pool_mlp<<<NG, 128, 0, stream>>>(bT, pw, l1W, l1b, l2W, l2b, l3W, l3b,
                                     (float*)d_out);
}

// Round 4
// 305.723 us; speedup vs baseline: 1.9879x; 1.3774x over previous
//
#include <hip/hip_runtime.h>
#include <math.h>

#define NN 32768
#define NG 256
#define DEG 8
#define HC 256
#define NCAT 1088          // Q(256)|K(256)|V(256)|S(768..1023)|QE(1024..1087)
#define KTOP 64
#define EPSBN 1e-5f

typedef __attribute__((ext_vector_type(8))) short short8v;   // 8 bf16
typedef __attribute__((ext_vector_type(4))) float f32x4;

// ---------------- bf16 helpers ----------------
__device__ inline float bf2f(unsigned short u) {
    union { unsigned int i; float f; } c; c.i = ((unsigned int)u) << 16; return c.f;
}
__device__ inline unsigned short f2bf(float f) {
    union { float f; unsigned int i; } c; c.f = f;
    unsigned int r = c.i + 0x7FFFu + ((c.i >> 16) & 1u);
    return (unsigned short)(r >> 16);
}
__device__ inline float4 load4bf(const unsigned short* p) {
    ushort4 u = *(const ushort4*)p;
    float4 r; r.x = bf2f(u.x); r.y = bf2f(u.y); r.z = bf2f(u.z); r.w = bf2f(u.w);
    return r;
}
// split v into hi + lo bf16 parts (hi = bf16(v), lo = bf16(v - hi))
__device__ inline void split2(float v, unsigned short& hi, unsigned short& lo) {
    hi = f2bf(v);
    lo = f2bf(v - bf2f(hi));
}

// ---------------------------------------------------------------------------
// prep: build transposed bf16 hi/lo weights.
//  WThi/WTlo [1088][64]; bcat[1088]; tWThi/tWTlo [64][256]
// ---------------------------------------------------------------------------
__global__ __launch_bounds__(256) void prep(
    const float* __restrict__ Wq, const float* __restrict__ bq,
    const float* __restrict__ Wk, const float* __restrict__ bk,
    const float* __restrict__ Wv, const float* __restrict__ bv,
    const float* __restrict__ Ws, const float* __restrict__ bs,
    const float* __restrict__ We, const float* __restrict__ tW,
    unsigned short* __restrict__ WThi, unsigned short* __restrict__ WTlo,
    float* __restrict__ bcat,
    unsigned short* __restrict__ tWThi, unsigned short* __restrict__ tWTlo)
{
    const int t = threadIdx.x, b = blockIdx.x;
    if (b < 16) {
        int n = b * 64 + (t >> 2);
        int cc = n & 255;
        const float* src = (n < 256) ? Wq : (n < 512) ? Wk : (n < 768) ? Wv : Ws;
        int k0 = (t & 3) * 16;
        for (int k = k0; k < k0 + 16; k++) {
            unsigned short h, l;
            split2(src[k * 256 + cc], h, l);
            WThi[n * 64 + k] = h; WTlo[n * 64 + k] = l;
        }
    } else if (b == 16) {
        for (int c = t; c < 1024; c += 256) {
            int cc = c & 255;
            bcat[c] = (c < 256) ? bq[cc] : (c < 512) ? bk[cc] : (c < 768) ? bv[cc] : bs[cc];
        }
        int o = t >> 2, h = o >> 4, f = o & 15;
        int k0 = (t & 3) * 16;
        for (int k = k0; k < k0 + 16; k++) {
            float s = 0.f;
            #pragma unroll
            for (int d = 0; d < 64; d++)
                s += Wq[k * 256 + h * 64 + d] * We[f * 256 + h * 64 + d];
            unsigned short hh, ll;
            split2(s, hh, ll);
            WThi[(1024 + o) * 64 + k] = hh; WTlo[(1024 + o) * 64 + k] = ll;
        }
        if ((t & 3) == 0) {
            float s = 0.f;
            #pragma unroll
            for (int d = 0; d < 64; d++)
                s += bq[h * 64 + d] * We[f * 256 + h * 64 + d];
            bcat[1024 + o] = s;
        }
    } else {
        int n = t >> 2;
        int k0 = (t & 3) * 64;
        for (int k = k0; k < k0 + 64; k++) {
            unsigned short h, l;
            split2(tW[k * 64 + n], h, l);
            tWThi[n * 256 + k] = h; tWTlo[n * 256 + k] = l;
        }
    }
}

// ---------------------------------------------------------------------------
// MFMA projection (split-bf16, ~fp32 accuracy):
//   C_bf16[M,1088] = A_f32[M,64] @ W[64,1088] + bcat
// 64x64 tile, 4 waves; acc += Ahi*Whi + Alo*Whi + Ahi*Wlo.
// ---------------------------------------------------------------------------
__global__ __launch_bounds__(256) void proj_mfma(
    const float* __restrict__ A,
    const unsigned short* __restrict__ WThi, const unsigned short* __restrict__ WTlo,
    const float* __restrict__ bcat, unsigned short* __restrict__ C)
{
    __shared__ char smem[32768];
    unsigned short* AhiL = (unsigned short*)smem;            // [64][64]
    unsigned short* AloL = AhiL + 4096;
    unsigned short* WhiL = AloL + 4096;
    unsigned short* WloL = WhiL + 4096;
    float* CL = (float*)smem;                                // [64][68] reuse
    const int t = threadIdx.x;
    const int n0 = blockIdx.x * 64;
    const int row0 = blockIdx.y * 64;

    #pragma unroll
    for (int g = 0; g < 2; g++) {
        int idx = t * 8 + g * 2048;
        int r = idx >> 6, c = idx & 63;
        int ch = (c >> 3) ^ (r & 7);
        float4 a0 = *(const float4*)(A + (size_t)(row0 + r) * 64 + c);
        float4 a1 = *(const float4*)(A + (size_t)(row0 + r) * 64 + c + 4);
        float av[8] = {a0.x, a0.y, a0.z, a0.w, a1.x, a1.y, a1.z, a1.w};
        short8v vh, vl;
        #pragma unroll
        for (int j = 0; j < 8; j++) {
            unsigned short h, l;
            split2(av[j], h, l);
            vh[j] = (short)h; vl[j] = (short)l;
        }
        *(short8v*)(AhiL + r * 64 + ch * 8) = vh;
        *(short8v*)(AloL + r * 64 + ch * 8) = vl;
        *(short8v*)(WhiL + r * 64 + ch * 8) =
            *(const short8v*)(WThi + (size_t)(n0 + r) * 64 + c);
        *(short8v*)(WloL + r * 64 + ch * 8) =
            *(const short8v*)(WTlo + (size_t)(n0 + r) * 64 + c);
    }
    __syncthreads();

    const int w = t >> 6, l = t & 63;
    const int lr = l & 15, lg = l >> 4, ls = l & 7;
    f32x4 acc[4] = {};
    #pragma unroll
    for (int kk = 0; kk < 2; kk++) {
        int ch = (kk * 4 + lg) ^ ls;
        short8v ah = *(short8v*)(AhiL + (w * 16 + lr) * 64 + ch * 8);
        short8v al = *(short8v*)(AloL + (w * 16 + lr) * 64 + ch * 8);
        #pragma unroll
        for (int nt = 0; nt < 4; nt++) {
            short8v bh = *(short8v*)(WhiL + (nt * 16 + lr) * 64 + ch * 8);
            short8v bl = *(short8v*)(WloL + (nt * 16 + lr) * 64 + ch * 8);
            acc[nt] = __builtin_amdgcn_mfma_f32_16x16x32_bf16(ah, bh, acc[nt], 0, 0, 0);
            acc[nt] = __builtin_amdgcn_mfma_f32_16x16x32_bf16(al, bh, acc[nt], 0, 0, 0);
            acc[nt] = __builtin_amdgcn_mfma_f32_16x16x32_bf16(ah, bl, acc[nt], 0, 0, 0);
        }
    }
    __syncthreads();
    #pragma unroll
    for (int nt = 0; nt < 4; nt++)
        #pragma unroll
        for (int r = 0; r < 4; r++)
            CL[(w * 16 + lg * 4 + r) * 68 + nt * 16 + lr] = acc[nt][r];
    __syncthreads();
    {
        int r = t >> 2, cb = (t & 3) * 16;
        #pragma unroll
        for (int jj = 0; jj < 2; jj++) {
            f32x4 p0 = *(f32x4*)(CL + r * 68 + cb + jj * 8);
            f32x4 p1 = *(f32x4*)(CL + r * 68 + cb + jj * 8 + 4);
            float4 b0 = *(const float4*)(bcat + n0 + cb + jj * 8);
            float4 b1 = *(const float4*)(bcat + n0 + cb + jj * 8 + 4);
            short8v o;
            o[0] = (short)f2bf(p0[0] + b0.x); o[1] = (short)f2bf(p0[1] + b0.y);
            o[2] = (short)f2bf(p0[2] + b0.z); o[3] = (short)f2bf(p0[3] + b0.w);
            o[4] = (short)f2bf(p1[0] + b1.x); o[5] = (short)f2bf(p1[1] + b1.y);
            o[6] = (short)f2bf(p1[2] + b1.z); o[7] = (short)f2bf(p1[3] + b1.w);
            *(short8v*)(C + (size_t)(row0 + r) * NCAT + n0 + cb + jj * 8) = o;
        }
    }
}

// ---------------------------------------------------------------------------
// MFMA transform (split-bf16): T_f32[M,64] = relu(H[M,256] @ tW[256,64] + b)
// H given as hi/lo bf16 pair.
// ---------------------------------------------------------------------------
__global__ __launch_bounds__(256) void gemm_t(
    const unsigned short* __restrict__ Ahi, const unsigned short* __restrict__ Alo,
    const unsigned short* __restrict__ WThi, const unsigned short* __restrict__ WTlo,
    const float* __restrict__ bias, float* __restrict__ Tout)
{
    __shared__ char smem[32768];
    unsigned short* AhiL = (unsigned short*)smem;
    unsigned short* AloL = AhiL + 4096;
    unsigned short* WhiL = AloL + 4096;
    unsigned short* WloL = WhiL + 4096;
    float* CL = (float*)smem;
    const int t = threadIdx.x;
    const int row0 = blockIdx.x * 64;
    const int w = t >> 6, l = t & 63;
    const int lr = l & 15, lg = l >> 4, ls = l & 7;
    f32x4 acc[4] = {};
    for (int kt = 0; kt < 4; kt++) {
        if (kt) __syncthreads();
        #pragma unroll
        for (int g = 0; g < 2; g++) {
            int idx = t * 8 + g * 2048;
            int r = idx >> 6, c = idx & 63;
            int ch = (c >> 3) ^ (r & 7);
            *(short8v*)(AhiL + r * 64 + ch * 8) =
                *(const short8v*)(Ahi + (size_t)(row0 + r) * 256 + kt * 64 + c);
            *(short8v*)(AloL + r * 64 + ch * 8) =
                *(const short8v*)(Alo + (size_t)(row0 + r) * 256 + kt * 64 + c);
            *(short8v*)(WhiL + r * 64 + ch * 8) =
                *(const short8v*)(WThi + r * 256 + kt * 64 + c);
            *(short8v*)(WloL + r * 64 + ch * 8) =
                *(const short8v*)(WTlo + r * 256 + kt * 64 + c);
        }
        __syncthreads();
        #pragma unroll
        for (int kk = 0; kk < 2; kk++) {
            int ch = (kk * 4 + lg) ^ ls;
            short8v ah = *(short8v*)(AhiL + (w * 16 + lr) * 64 + ch * 8);
            short8v al = *(short8v*)(AloL + (w * 16 + lr) * 64 + ch * 8);
            #pragma unroll
            for (int nt = 0; nt < 4; nt++) {
                short8v bh = *(short8v*)(WhiL + (nt * 16 + lr) * 64 + ch * 8);
                short8v bl = *(short8v*)(WloL + (nt * 16 + lr) * 64 + ch * 8);
                acc[nt] = __builtin_amdgcn_mfma_f32_16x16x32_bf16(ah, bh, acc[nt], 0, 0, 0);
                acc[nt] = __builtin_amdgcn_mfma_f32_16x16x32_bf16(al, bh, acc[nt], 0, 0, 0);
                acc[nt] = __builtin_amdgcn_mfma_f32_16x16x32_bf16(ah, bl, acc[nt], 0, 0, 0);
            }
        }
    }
    __syncthreads();
    #pragma unroll
    for (int nt = 0; nt < 4; nt++)
        #pragma unroll
        for (int r = 0; r < 4; r++)
            CL[(w * 16 + lg * 4 + r) * 68 + nt * 16 + lr] = acc[nt][r];
    __syncthreads();
    {
        int r = t >> 2, cb = (t & 3) * 16;
        #pragma unroll
        for (int jj = 0; jj < 4; jj++) {
            f32x4 p = *(f32x4*)(CL + r * 68 + cb + jj * 4);
            float4 bb = *(const float4*)(bias + cb + jj * 4);
            float4 o;
            o.x = fmaxf(p[0] + bb.x, 0.f); o.y = fmaxf(p[1] + bb.y, 0.f);
            o.z = fmaxf(p[2] + bb.z, 0.f); o.w = fmaxf(p[3] + bb.w, 0.f);
            *(float4*)(Tout + (size_t)(row0 + r) * 64 + cb + jj * 4) = o;
        }
    }
}

// ---------------------------------------------------------------------------
// Factored attention + beta gate. One 64-lane wave per node.
// Output H written as bf16 hi/lo pair (≈fp32 for downstream GEMM).
// ---------------------------------------------------------------------------
__global__ __launch_bounds__(256) void attn_fused(
    const unsigned short* __restrict__ C,
    const float* __restrict__ We, const float* __restrict__ Wb,
    const int* __restrict__ srcIdx, const float* __restrict__ EA,
    unsigned short* __restrict__ Hhi, unsigned short* __restrict__ Hlo)
{
    __shared__ float WeL[16 * 256];
    for (int i = threadIdx.x; i < 16 * 256; i += 256) WeL[i] = We[i];
    __syncthreads();
    const int lane = threadIdx.x & 63;
    const int wave = threadIdx.x >> 6;
    const int bid = blockIdx.x;
    const int swz = (bid & 7) * 1024 + (bid >> 3);
    const int n = swz * 4 + wave;
    const int fl = lane & 15;
    const int c0 = lane * 4;

    const unsigned short* rowN = C + (size_t)n * NCAT;
    float4 q = load4bf(rowN + c0);
    float qe_l = bf2f(rowN[1024 + (lane >> 4) * 16 + fl]);

    float4 v4[DEG];
    float eas[DEG], alpha[DEG];
    const int ebase = n * DEG;
    #pragma unroll
    for (int j = 0; j < DEG; j++) {
        int s = srcIdx[ebase + j];
        const unsigned short* rowS = C + (size_t)s * NCAT;
        float4 k4 = load4bf(rowS + 256 + c0);
        v4[j] = load4bf(rowS + 512 + c0);
        eas[j] = EA[(size_t)(ebase + j) * 16 + fl];
        float d = q.x*k4.x + q.y*k4.y + q.z*k4.z + q.w*k4.w + eas[j] * qe_l;
        d += __shfl_xor(d, 1); d += __shfl_xor(d, 2);
        d += __shfl_xor(d, 4); d += __shfl_xor(d, 8);
        alpha[j] = d * 0.125f;
    }
    float mx = alpha[0];
    #pragma unroll
    for (int j = 1; j < DEG; j++) mx = fmaxf(mx, alpha[j]);
    float wsum = 0.f, wgt[DEG];
    #pragma unroll
    for (int j = 0; j < DEG; j++) { wgt[j] = expf(alpha[j] - mx); wsum += wgt[j]; }
    float inv = 1.f / wsum;

    float eagg = 0.f;
    float ox = 0.f, oy = 0.f, oz = 0.f, ow = 0.f;
    #pragma unroll
    for (int j = 0; j < DEG; j++) {
        float wj = wgt[j] * inv;
        eagg += wj * eas[j];
        ox += wj*v4[j].x; oy += wj*v4[j].y; oz += wj*v4[j].z; ow += wj*v4[j].w;
    }
    const float4* WeL4 = (const float4*)WeL;
    #pragma unroll
    for (int f = 0; f < 16; f++) {
        float a = __shfl(eagg, f, 16);
        float4 wv = WeL4[f * 64 + lane];
        ox += a * wv.x; oy += a * wv.y; oz += a * wv.z; ow += a * wv.w;
    }

    float4 xr = load4bf(rowN + 768 + c0);
    float part = ox*Wb[c0+0] + oy*Wb[c0+1] + oz*Wb[c0+2] + ow*Wb[c0+3]
               + xr.x*Wb[256+c0+0] + xr.y*Wb[256+c0+1]
               + xr.z*Wb[256+c0+2] + xr.w*Wb[256+c0+3]
               + (ox-xr.x)*Wb[512+c0+0] + (oy-xr.y)*Wb[512+c0+1]
               + (oz-xr.z)*Wb[512+c0+2] + (ow-xr.w)*Wb[512+c0+3];
    part += __shfl_xor(part, 1);  part += __shfl_xor(part, 2);
    part += __shfl_xor(part, 4);  part += __shfl_xor(part, 8);
    part += __shfl_xor(part, 16); part += __shfl_xor(part, 32);
    float beta = 1.f / (1.f + expf(-part));
    float hv[4];
    hv[0] = beta*xr.x + (1.f-beta)*ox;
    hv[1] = beta*xr.y + (1.f-beta)*oy;
    hv[2] = beta*xr.z + (1.f-beta)*oz;
    hv[3] = beta*xr.w + (1.f-beta)*ow;
    ushort4 hh, hl;
    split2(hv[0], hh.x, hl.x); split2(hv[1], hh.y, hl.y);
    split2(hv[2], hh.z, hl.z); split2(hv[3], hh.w, hl.w);
    *(ushort4*)(Hhi + (size_t)n * HC + c0) = hh;
    *(ushort4*)(Hlo + (size_t)n * HC + c0) = hl;
}

// ---------------------------------------------------------------------------
// BatchNorm helpers (fp32 in place)
// ---------------------------------------------------------------------------
__global__ void zero_stats(float* __restrict__ s) { s[threadIdx.x] = 0.f; }

__global__ __launch_bounds__(256) void bn_stats(
    const float* __restrict__ T, float* __restrict__ stats)
{
    const int c = threadIdx.x & 63;
    const int rg = threadIdx.x >> 6;
    float s = 0.f, s2 = 0.f;
    for (int r = blockIdx.x * 4 + rg; r < NN; r += gridDim.x * 4) {
        float v = T[(size_t)r * 64 + c];
        s += v; s2 += v * v;
    }
    __shared__ float red[256], red2[256];
    red[threadIdx.x] = s; red2[threadIdx.x] = s2;
    __syncthreads();
    if (threadIdx.x < 64) {
        s  = red[c]  + red[64+c]  + red[128+c]  + red[192+c];
        s2 = red2[c] + red2[64+c] + red2[128+c] + red2[192+c];
        atomicAdd(&stats[c], s);
        atomicAdd(&stats[64 + c], s2);
    }
}

__global__ __launch_bounds__(256) void bn_apply(
    float* __restrict__ T, const float* __restrict__ stats,
    const float* __restrict__ g, const float* __restrict__ b)
{
    int i = blockIdx.x * 256 + threadIdx.x;
    int c = i & 63;
    float mean = stats[c] * (1.f / NN);
    float var  = stats[64 + c] * (1.f / NN) - mean * mean;
    float v = T[i];
    T[i] = g[c] * (v - mean) * rsqrtf(var + EPSBN) + b[c];
}

// ---------------------------------------------------------------------------
// TopK pooling + readout + MLP head. One block (128 threads) per graph.
// ---------------------------------------------------------------------------
__global__ __launch_bounds__(128) void pool_mlp(
    const float* __restrict__ Hn, const float* __restrict__ pw,
    const float* __restrict__ W1, const float* __restrict__ b1,
    const float* __restrict__ W2, const float* __restrict__ b2,
    const float* __restrict__ W3, const float* __restrict__ b3,
    float* __restrict__ out)
{
    __shared__ float sh[128][65];
    __shared__ float spw[64];
    __shared__ float sc[128];
    __shared__ float sscale[128];
    __shared__ int   skeep[128];
    __shared__ float rmax[2][64], rsum[2][64];
    __shared__ float srep[128];
    __shared__ float sh1[256];
    __shared__ float sh2[128];
    __shared__ float wred[2];
    const int g = blockIdx.x, t = threadIdx.x;

    for (int i = t; i < 128 * 64; i += 128) sh[i >> 6][i & 63] = Hn[(size_t)g * 128 * 64 + i];
    if (t < 64) spw[t] = pw[t];
    __syncthreads();

    float nw = 0.f;
    #pragma unroll
    for (int i = 0; i < 64; i++) { float w = spw[i]; nw += w * w; }
    float invn = rsqrtf(nw);

    float s = 0.f;
    #pragma unroll
    for (int i = 0; i < 64; i++) s += sh[t][i] * spw[i];
    s *= invn;
    sc[t] = s;
    __syncthreads();

    int rank = 0;
    for (int m = 0; m < 128; m++) {
        float sm = sc[m];
        rank += (sm > s) || (sm == s && m < t);
    }
    skeep[t] = (rank < KTOP);
    sscale[t] = tanhf(s);
    __syncthreads();

    {
        int c = t & 63, half = t >> 6;
        float mxv = -1e30f, sm = 0.f;
        for (int r = half * 64; r < half * 64 + 64; r++) {
            if (skeep[r]) {
                float v = sh[r][c] * sscale[r];
                mxv = fmaxf(mxv, v); sm += v;
            }
        }
        rmax[half][c] = mxv; rsum[half][c] = sm;
    }
    __syncthreads();
    if (t < 64) {
        srep[t] = fmaxf(rmax[0][t], rmax[1][t]);
        srep[64 + t] = (rsum[0][t] + rsum[1][t]) * (1.f / KTOP);
    }
    __syncthreads();

    #pragma unroll
    for (int jj = 0; jj < 2; jj++) {
        int j = t + jj * 128;
        float a = b1[j];
        for (int c2 = 0; c2 < 128; c2++) a += srep[c2] * W1[c2 * 256 + j];
        sh1[j] = fmaxf(a, 0.f);
    }
    __syncthreads();
    {
        float a = b2[t];
        for (int c2 = 0; c2 < 256; c2++) a += sh1[c2] * W2[c2 * 128 + t];
        sh2[t] = fmaxf(a, 0.f);
    }
    __syncthreads();
    float p = sh2[t] * W3[t];
    p += __shfl_xor(p, 1);  p += __shfl_xor(p, 2);  p += __shfl_xor(p, 4);
    p += __shfl_xor(p, 8);  p += __shfl_xor(p, 16); p += __shfl_xor(p, 32);
    if ((t & 63) == 0) wred[t >> 6] = p;
    __syncthreads();
    if (t == 0) out[g] = wred[0] + wred[1] + b3[0];
}

// ---------------------------------------------------------------------------
extern "C" void kernel_launch(void* const* d_in, const int* in_sizes, int n_in,
                              void* d_out, int out_size, void* d_ws, size_t ws_size,
                              hipStream_t stream)
{
    const float* x    = (const float*)d_in[0];
    const int*   ei   = (const int*)  d_in[1];
    const float* ea   = (const float*)d_in[2];
    const int*   srcI = ei;
    const float* Wq1 = (const float*)d_in[4];  const float* bq1 = (const float*)d_in[5];
    const float* Wk1 = (const float*)d_in[6];  const float* bk1 = (const float*)d_in[7];
    const float* Wv1 = (const float*)d_in[8];  const float* bv1 = (const float*)d_in[9];
    const float* We1 = (const float*)d_in[10];
    const float* Ws1 = (const float*)d_in[11]; const float* bs1 = (const float*)d_in[12];
    const float* Wb1 = (const float*)d_in[13];
    const float* t1W = (const float*)d_in[14]; const float* t1b = (const float*)d_in[15];
    const float* g1  = (const float*)d_in[16]; const float* be1 = (const float*)d_in[17];
    const float* Wq2 = (const float*)d_in[18]; const float* bq2 = (const float*)d_in[19];
    const float* Wk2 = (const float*)d_in[20]; const float* bk2 = (const float*)d_in[21];
    const float* Wv2 = (const float*)d_in[22]; const float* bv2 = (const float*)d_in[23];
    const float* We2 = (const float*)d_in[24];
    const float* Ws2 = (const float*)d_in[25]; const float* bs2 = (const float*)d_in[26];
    const float* Wb2 = (const float*)d_in[27];
    const float* t2W = (const float*)d_in[28]; const float* t2b = (const float*)d_in[29];
    const float* g2  = (const float*)d_in[30]; const float* be2 = (const float*)d_in[31];
    const float* pw  = (const float*)d_in[32];
    const float* l1W = (const float*)d_in[33]; const float* l1b = (const float*)d_in[34];
    const float* l2W = (const float*)d_in[35]; const float* l2b = (const float*)d_in[36];
    const float* l3W = (const float*)d_in[37]; const float* l3b = (const float*)d_in[38];

    char* ws = (char*)d_ws;
    unsigned short* C   = (unsigned short*)ws;                     // [NN,1088] bf16
    unsigned short* Hhi = (unsigned short*)(ws + (size_t)NN * NCAT * 2);
    unsigned short* Hlo = Hhi + (size_t)NN * HC;
    float* bT    = (float*)(Hlo + (size_t)NN * HC);                // [NN,64] f32
    float* bcat  = bT + (size_t)NN * 64;                           // [1088]
    float* stats = bcat + NCAT;                                    // [128]
    unsigned short* WThi  = (unsigned short*)(stats + 128);        // [1088][64]
    unsigned short* WTlo  = WThi + (size_t)NCAT * 64;
    unsigned short* tWThi = WTlo + (size_t)NCAT * 64;              // [64][256]
    unsigned short* tWTlo = tWThi + 64 * 256;

    const dim3 blk(256);
    const dim3 gProj(17, 512);

    // ---- layer 1 ----
    prep<<<18, blk, 0, stream>>>(Wq1, bq1, Wk1, bk1, Wv1, bv1, Ws1, bs1, We1, t1W,
                                 WThi, WTlo, bcat, tWThi, tWTlo);
    proj_mfma<<<gProj, blk, 0, stream>>>(x, WThi, WTlo, bcat, C);
    attn_fused<<<NN / 4, blk, 0, stream>>>(C, We1, Wb1, srcI, ea, Hhi, Hlo);
    gemm_t<<<512, blk, 0, stream>>>(Hhi, Hlo, tWThi, tWTlo, t1b, bT);
    zero_stats<<<1, 128, 0, stream>>>(stats);
    bn_stats<<<256, blk, 0, stream>>>(bT, stats);
    bn_apply<<<NN * 64 / 256, blk, 0, stream>>>(bT, stats, g1, be1);

    // ---- layer 2 ----
    prep<<<18, blk, 0, stream>>>(Wq2, bq2, Wk2, bk2, Wv2, bv2, Ws2, bs2, We2, t2W,
                                 WThi, WTlo, bcat, tWThi, tWTlo);
    proj_mfma<<<gProj, blk, 0, stream>>>(bT, WThi, WTlo, bcat, C);
    attn_fused<<<NN / 4, blk, 0, stream>>>(C, We2, Wb2, srcI, ea, Hhi, Hlo);
    gemm_t<<<512, blk, 0, stream>>>(Hhi, Hlo, tWThi, tWTlo, t2b, bT);
    zero_stats<<<1, 128, 0, stream>>>(stats);
    bn_stats<<<256, blk, 0, stream>>>(bT, stats);
    bn_apply<<<NN * 64 / 256, blk, 0, stream>>>(bT, stats, g2, be2);

    // ---- pooling + head ----
    pool_mlp<<<NG, 128, 0, stream>>>(bT, pw, l1W, l1b, l2W, l2b, l3W, l3b,
                                     (float*)d_out);
}

// Round 5
// 299.411 us; speedup vs baseline: 2.0298x; 1.0211x over previous
//
#include <hip/hip_runtime.h>
#include <math.h>

#define NN 32768
#define NG 256
#define DEG 8
#define HC 256
#define NCAT 1088          // Q(256)|K(256)|V(256)|S(768..1023)|QE(1024..1087)
#define KTOP 64
#define EPSBN 1e-5f

typedef __attribute__((ext_vector_type(8))) short short8v;   // 8 bf16
typedef __attribute__((ext_vector_type(4))) float f32x4;

// ---------------- bf16 helpers ----------------
__device__ inline float bf2f(unsigned short u) {
    union { unsigned int i; float f; } c; c.i = ((unsigned int)u) << 16; return c.f;
}
__device__ inline unsigned short f2bf(float f) {
    union { float f; unsigned int i; } c; c.f = f;
    unsigned int r = c.i + 0x7FFFu + ((c.i >> 16) & 1u);
    return (unsigned short)(r >> 16);
}
__device__ inline void split2(float v, unsigned short& hi, unsigned short& lo) {
    hi = f2bf(v);
    lo = f2bf(v - bf2f(hi));
}

// ---------------------------------------------------------------------------
// split_x: fp32 [NN,64] -> hi/lo bf16 pair (one-time, layer-1 A operand)
// ---------------------------------------------------------------------------
__global__ __launch_bounds__(256) void split_x(
    const float* __restrict__ X,
    unsigned short* __restrict__ Xhi, unsigned short* __restrict__ Xlo)
{
    size_t i8 = ((size_t)blockIdx.x * 256 + threadIdx.x) * 8;
    float4 a0 = *(const float4*)(X + i8);
    float4 a1 = *(const float4*)(X + i8 + 4);
    float av[8] = {a0.x, a0.y, a0.z, a0.w, a1.x, a1.y, a1.z, a1.w};
    short8v vh, vl;
    #pragma unroll
    for (int j = 0; j < 8; j++) {
        unsigned short h, l;
        split2(av[j], h, l);
        vh[j] = (short)h; vl[j] = (short)l;
    }
    *(short8v*)(Xhi + i8) = vh;
    *(short8v*)(Xlo + i8) = vl;
}

// ---------------------------------------------------------------------------
// prep: transposed bf16 hi/lo weights. WThi/WTlo [1088][64]; bcat[1088];
// tWThi/tWTlo [64][256]
// ---------------------------------------------------------------------------
__global__ __launch_bounds__(256) void prep(
    const float* __restrict__ Wq, const float* __restrict__ bq,
    const float* __restrict__ Wk, const float* __restrict__ bk,
    const float* __restrict__ Wv, const float* __restrict__ bv,
    const float* __restrict__ Ws, const float* __restrict__ bs,
    const float* __restrict__ We, const float* __restrict__ tW,
    unsigned short* __restrict__ WThi, unsigned short* __restrict__ WTlo,
    float* __restrict__ bcat,
    unsigned short* __restrict__ tWThi, unsigned short* __restrict__ tWTlo)
{
    const int t = threadIdx.x, b = blockIdx.x;
    if (b < 16) {
        int n = b * 64 + (t >> 2);
        int cc = n & 255;
        const float* src = (n < 256) ? Wq : (n < 512) ? Wk : (n < 768) ? Wv : Ws;
        int k0 = (t & 3) * 16;
        for (int k = k0; k < k0 + 16; k++) {
            unsigned short h, l;
            split2(src[k * 256 + cc], h, l);
            WThi[n * 64 + k] = h; WTlo[n * 64 + k] = l;
        }
    } else if (b == 16) {
        for (int c = t; c < 1024; c += 256) {
            int cc = c & 255;
            bcat[c] = (c < 256) ? bq[cc] : (c < 512) ? bk[cc] : (c < 768) ? bv[cc] : bs[cc];
        }
        int o = t >> 2, h = o >> 4, f = o & 15;
        int k0 = (t & 3) * 16;
        for (int k = k0; k < k0 + 16; k++) {
            float s = 0.f;
            #pragma unroll
            for (int d = 0; d < 64; d++)
                s += Wq[k * 256 + h * 64 + d] * We[f * 256 + h * 64 + d];
            unsigned short hh, ll;
            split2(s, hh, ll);
            WThi[(1024 + o) * 64 + k] = hh; WTlo[(1024 + o) * 64 + k] = ll;
        }
        if ((t & 3) == 0) {
            float s = 0.f;
            #pragma unroll
            for (int d = 0; d < 64; d++)
                s += bq[h * 64 + d] * We[f * 256 + h * 64 + d];
            bcat[1024 + o] = s;
        }
    } else {
        int n = t >> 2;
        int k0 = (t & 3) * 64;
        for (int k = k0; k < k0 + 64; k++) {
            unsigned short h, l;
            split2(tW[k * 64 + n], h, l);
            tWThi[n * 256 + k] = h; tWTlo[n * 256 + k] = l;
        }
    }
}

// ---------------------------------------------------------------------------
// MFMA projection (split-bf16): C_bf16[M,1088] = A[M,64] @ W[64,1088] + bcat
// A pre-split hi/lo bf16. 64x64 tile, 4 waves.
// ---------------------------------------------------------------------------
__global__ __launch_bounds__(256) void proj_mfma(
    const unsigned short* __restrict__ Ahi, const unsigned short* __restrict__ Alo,
    const unsigned short* __restrict__ WThi, const unsigned short* __restrict__ WTlo,
    const float* __restrict__ bcat, unsigned short* __restrict__ C)
{
    __shared__ char smem[32768];
    unsigned short* AhiL = (unsigned short*)smem;            // [64][64]
    unsigned short* AloL = AhiL + 4096;
    unsigned short* WhiL = AloL + 4096;
    unsigned short* WloL = WhiL + 4096;
    float* CL = (float*)smem;                                // [64][68] reuse
    const int t = threadIdx.x;
    const int n0 = blockIdx.x * 64;
    const int row0 = blockIdx.y * 64;

    #pragma unroll
    for (int g = 0; g < 2; g++) {
        int idx = t * 8 + g * 2048;
        int r = idx >> 6, c = idx & 63;
        int ch = (c >> 3) ^ (r & 7);
        *(short8v*)(AhiL + r * 64 + ch * 8) =
            *(const short8v*)(Ahi + (size_t)(row0 + r) * 64 + c);
        *(short8v*)(AloL + r * 64 + ch * 8) =
            *(const short8v*)(Alo + (size_t)(row0 + r) * 64 + c);
        *(short8v*)(WhiL + r * 64 + ch * 8) =
            *(const short8v*)(WThi + (size_t)(n0 + r) * 64 + c);
        *(short8v*)(WloL + r * 64 + ch * 8) =
            *(const short8v*)(WTlo + (size_t)(n0 + r) * 64 + c);
    }
    __syncthreads();

    const int w = t >> 6, l = t & 63;
    const int lr = l & 15, lg = l >> 4, ls = l & 7;
    f32x4 acc[4] = {};
    #pragma unroll
    for (int kk = 0; kk < 2; kk++) {
        int ch = (kk * 4 + lg) ^ ls;
        short8v ah = *(short8v*)(AhiL + (w * 16 + lr) * 64 + ch * 8);
        short8v al = *(short8v*)(AloL + (w * 16 + lr) * 64 + ch * 8);
        #pragma unroll
        for (int nt = 0; nt < 4; nt++) {
            short8v bh = *(short8v*)(WhiL + (nt * 16 + lr) * 64 + ch * 8);
            short8v bl = *(short8v*)(WloL + (nt * 16 + lr) * 64 + ch * 8);
            acc[nt] = __builtin_amdgcn_mfma_f32_16x16x32_bf16(ah, bh, acc[nt], 0, 0, 0);
            acc[nt] = __builtin_amdgcn_mfma_f32_16x16x32_bf16(al, bh, acc[nt], 0, 0, 0);
            acc[nt] = __builtin_amdgcn_mfma_f32_16x16x32_bf16(ah, bl, acc[nt], 0, 0, 0);
        }
    }
    __syncthreads();
    #pragma unroll
    for (int nt = 0; nt < 4; nt++)
        #pragma unroll
        for (int r = 0; r < 4; r++)
            CL[(w * 16 + lg * 4 + r) * 68 + nt * 16 + lr] = acc[nt][r];
    __syncthreads();
    {
        int r = t >> 2, cb = (t & 3) * 16;
        #pragma unroll
        for (int jj = 0; jj < 2; jj++) {
            f32x4 p0 = *(f32x4*)(CL + r * 68 + cb + jj * 8);
            f32x4 p1 = *(f32x4*)(CL + r * 68 + cb + jj * 8 + 4);
            float4 b0 = *(const float4*)(bcat + n0 + cb + jj * 8);
            float4 b1 = *(const float4*)(bcat + n0 + cb + jj * 8 + 4);
            short8v o;
            o[0] = (short)f2bf(p0[0] + b0.x); o[1] = (short)f2bf(p0[1] + b0.y);
            o[2] = (short)f2bf(p0[2] + b0.z); o[3] = (short)f2bf(p0[3] + b0.w);
            o[4] = (short)f2bf(p1[0] + b1.x); o[5] = (short)f2bf(p1[1] + b1.y);
            o[6] = (short)f2bf(p1[2] + b1.z); o[7] = (short)f2bf(p1[3] + b1.w);
            *(short8v*)(C + (size_t)(row0 + r) * NCAT + n0 + cb + jj * 8) = o;
        }
    }
}

// ---------------------------------------------------------------------------
// MFMA transform (split-bf16): T_f32[M,64] = relu(H[M,256] @ tW[256,64] + b)
// ---------------------------------------------------------------------------
__global__ __launch_bounds__(256) void gemm_t(
    const unsigned short* __restrict__ Ahi, const unsigned short* __restrict__ Alo,
    const unsigned short* __restrict__ WThi, const unsigned short* __restrict__ WTlo,
    const float* __restrict__ bias, float* __restrict__ Tout)
{
    __shared__ char smem[32768];
    unsigned short* AhiL = (unsigned short*)smem;
    unsigned short* AloL = AhiL + 4096;
    unsigned short* WhiL = AloL + 4096;
    unsigned short* WloL = WhiL + 4096;
    float* CL = (float*)smem;
    const int t = threadIdx.x;
    const int row0 = blockIdx.x * 64;
    const int w = t >> 6, l = t & 63;
    const int lr = l & 15, lg = l >> 4, ls = l & 7;
    f32x4 acc[4] = {};
    for (int kt = 0; kt < 4; kt++) {
        if (kt) __syncthreads();
        #pragma unroll
        for (int g = 0; g < 2; g++) {
            int idx = t * 8 + g * 2048;
            int r = idx >> 6, c = idx & 63;
            int ch = (c >> 3) ^ (r & 7);
            *(short8v*)(AhiL + r * 64 + ch * 8) =
                *(const short8v*)(Ahi + (size_t)(row0 + r) * 256 + kt * 64 + c);
            *(short8v*)(AloL + r * 64 + ch * 8) =
                *(const short8v*)(Alo + (size_t)(row0 + r) * 256 + kt * 64 + c);
            *(short8v*)(WhiL + r * 64 + ch * 8) =
                *(const short8v*)(WThi + r * 256 + kt * 64 + c);
            *(short8v*)(WloL + r * 64 + ch * 8) =
                *(const short8v*)(WTlo + r * 256 + kt * 64 + c);
        }
        __syncthreads();
        #pragma unroll
        for (int kk = 0; kk < 2; kk++) {
            int ch = (kk * 4 + lg) ^ ls;
            short8v ah = *(short8v*)(AhiL + (w * 16 + lr) * 64 + ch * 8);
            short8v al = *(short8v*)(AloL + (w * 16 + lr) * 64 + ch * 8);
            #pragma unroll
            for (int nt = 0; nt < 4; nt++) {
                short8v bh = *(short8v*)(WhiL + (nt * 16 + lr) * 64 + ch * 8);
                short8v bl = *(short8v*)(WloL + (nt * 16 + lr) * 64 + ch * 8);
                acc[nt] = __builtin_amdgcn_mfma_f32_16x16x32_bf16(ah, bh, acc[nt], 0, 0, 0);
                acc[nt] = __builtin_amdgcn_mfma_f32_16x16x32_bf16(al, bh, acc[nt], 0, 0, 0);
                acc[nt] = __builtin_amdgcn_mfma_f32_16x16x32_bf16(ah, bl, acc[nt], 0, 0, 0);
            }
        }
    }
    __syncthreads();
    #pragma unroll
    for (int nt = 0; nt < 4; nt++)
        #pragma unroll
        for (int r = 0; r < 4; r++)
            CL[(w * 16 + lg * 4 + r) * 68 + nt * 16 + lr] = acc[nt][r];
    __syncthreads();
    {
        int r = t >> 2, cb = (t & 3) * 16;
        #pragma unroll
        for (int jj = 0; jj < 4; jj++) {
            f32x4 p = *(f32x4*)(CL + r * 68 + cb + jj * 4);
            float4 bb = *(const float4*)(bias + cb + jj * 4);
            float4 o;
            o.x = fmaxf(p[0] + bb.x, 0.f); o.y = fmaxf(p[1] + bb.y, 0.f);
            o.z = fmaxf(p[2] + bb.z, 0.f); o.w = fmaxf(p[3] + bb.w, 0.f);
            *(float4*)(Tout + (size_t)(row0 + r) * 64 + cb + jj * 4) = o;
        }
    }
}

// ---------------------------------------------------------------------------
// Attention + beta gate. 2 nodes per wave: 32 lanes/node, 8 channels/lane.
// Row layout in C: [Q|K|V|S|QE]. Output H as bf16 hi/lo pair.
// ---------------------------------------------------------------------------
__global__ __launch_bounds__(256) void attn_fused(
    const unsigned short* __restrict__ C,
    const float* __restrict__ We, const float* __restrict__ Wb,
    const int* __restrict__ srcIdx, const float* __restrict__ EA,
    unsigned short* __restrict__ Hhi, unsigned short* __restrict__ Hlo)
{
    __shared__ float WeL[16 * 256];
    for (int i = threadIdx.x; i < 16 * 256; i += 256) WeL[i] = We[i];
    __syncthreads();
    const int t = threadIdx.x;
    const int lane = t & 63;
    const int bid = blockIdx.x;
    const int swz = (bid & 7) * 512 + (bid >> 3);   // 4096 blocks -> XCD chunks
    const int n = swz * 8 + (t >> 5);               // 8 nodes per block
    const int l = lane & 31;                        // lane within node
    const int c0 = l * 8;                           // 8 channels
    const int h = l >> 3;                           // head
    const int fl = l & 7;                           // feature-pair / edge slot
    const int gb = lane & 56;                       // 8-lane head-group base

    const unsigned short* rowN = C + (size_t)n * NCAT;
    short8v qv = *(const short8v*)(rowN + c0);
    float q[8];
    #pragma unroll
    for (int i = 0; i < 8; i++) q[i] = bf2f((unsigned short)qv[i]);
    float qe0 = bf2f(rowN[1024 + h * 16 + 2 * fl]);
    float qe1 = bf2f(rowN[1024 + h * 16 + 2 * fl + 1]);

    const int ebase = n * DEG;
    int sj = srcIdx[ebase + fl];

    short8v vv[DEG];
    float ea0[DEG], ea1[DEG], alpha[DEG];
    #pragma unroll
    for (int j = 0; j < DEG; j++) {
        int s = __shfl(sj, gb | j);
        const unsigned short* rowS = C + (size_t)s * NCAT;
        short8v kv = *(const short8v*)(rowS + 256 + c0);
        vv[j] = *(const short8v*)(rowS + 512 + c0);
        float2 ea = *(const float2*)(EA + (size_t)(ebase + j) * 16 + 2 * fl);
        ea0[j] = ea.x; ea1[j] = ea.y;
        float d = ea.x * qe0 + ea.y * qe1;
        #pragma unroll
        for (int i = 0; i < 8; i++) d += q[i] * bf2f((unsigned short)kv[i]);
        d += __shfl_xor(d, 1); d += __shfl_xor(d, 2); d += __shfl_xor(d, 4);
        alpha[j] = d * 0.125f;   // 1/sqrt(64)
    }
    float mx = alpha[0];
    #pragma unroll
    for (int j = 1; j < DEG; j++) mx = fmaxf(mx, alpha[j]);
    float wsum = 0.f, wgt[DEG];
    #pragma unroll
    for (int j = 0; j < DEG; j++) { wgt[j] = expf(alpha[j] - mx); wsum += wgt[j]; }
    float inv = 1.f / wsum;

    float o[8] = {};
    float eg0 = 0.f, eg1 = 0.f;
    #pragma unroll
    for (int j = 0; j < DEG; j++) {
        float wj = wgt[j] * inv;
        eg0 += wj * ea0[j]; eg1 += wj * ea1[j];
        #pragma unroll
        for (int i = 0; i < 8; i++) o[i] += wj * bf2f((unsigned short)vv[j][i]);
    }
    #pragma unroll
    for (int f = 0; f < 16; f++) {
        float a = __shfl((f & 1) ? eg1 : eg0, gb | (f >> 1));
        const float* wrow = WeL + f * 256 + c0;
        f32x4 w0 = *(const f32x4*)(wrow);
        f32x4 w1 = *(const f32x4*)(wrow + 4);
        o[0] += a * w0[0]; o[1] += a * w0[1]; o[2] += a * w0[2]; o[3] += a * w0[3];
        o[4] += a * w1[0]; o[5] += a * w1[1]; o[6] += a * w1[2]; o[7] += a * w1[3];
    }

    short8v sv = *(const short8v*)(rowN + 768 + c0);
    float xr[8];
    #pragma unroll
    for (int i = 0; i < 8; i++) xr[i] = bf2f((unsigned short)sv[i]);
    float part = 0.f;
    {
        f32x4 wo0 = *(const f32x4*)(Wb + c0);
        f32x4 wo1 = *(const f32x4*)(Wb + c0 + 4);
        f32x4 wx0 = *(const f32x4*)(Wb + 256 + c0);
        f32x4 wx1 = *(const f32x4*)(Wb + 256 + c0 + 4);
        f32x4 wd0 = *(const f32x4*)(Wb + 512 + c0);
        f32x4 wd1 = *(const f32x4*)(Wb + 512 + c0 + 4);
        #pragma unroll
        for (int i = 0; i < 4; i++) {
            part += o[i] * wo0[i] + xr[i] * wx0[i] + (o[i] - xr[i]) * wd0[i];
            part += o[4+i] * wo1[i] + xr[4+i] * wx1[i] + (o[4+i] - xr[4+i]) * wd1[i];
        }
    }
    part += __shfl_xor(part, 1);  part += __shfl_xor(part, 2);
    part += __shfl_xor(part, 4);  part += __shfl_xor(part, 8);
    part += __shfl_xor(part, 16);
    float beta = 1.f / (1.f + expf(-part));
    short8v hh, hl;
    #pragma unroll
    for (int i = 0; i < 8; i++) {
        float hv = beta * xr[i] + (1.f - beta) * o[i];
        unsigned short a, b;
        split2(hv, a, b);
        hh[i] = (short)a; hl[i] = (short)b;
    }
    *(short8v*)(Hhi + (size_t)n * HC + c0) = hh;
    *(short8v*)(Hlo + (size_t)n * HC + c0) = hl;
}

// ---------------------------------------------------------------------------
// BatchNorm helpers
// ---------------------------------------------------------------------------
__global__ void zero_stats(float* __restrict__ s) { s[threadIdx.x] = 0.f; }

__global__ __launch_bounds__(256) void bn_stats(
    const float* __restrict__ T, float* __restrict__ stats)
{
    const int c = threadIdx.x & 63;
    const int rg = threadIdx.x >> 6;
    float s = 0.f, s2 = 0.f;
    for (int r = blockIdx.x * 4 + rg; r < NN; r += gridDim.x * 4) {
        float v = T[(size_t)r * 64 + c];
        s += v; s2 += v * v;
    }
    __shared__ float red[256], red2[256];
    red[threadIdx.x] = s; red2[threadIdx.x] = s2;
    __syncthreads();
    if (threadIdx.x < 64) {
        s  = red[c]  + red[64+c]  + red[128+c]  + red[192+c];
        s2 = red2[c] + red2[64+c] + red2[128+c] + red2[192+c];
        atomicAdd(&stats[c], s);
        atomicAdd(&stats[64 + c], s2);
    }
}

// normalize in place (f32) + emit bf16 hi/lo for the next layer's A operand
__global__ __launch_bounds__(256) void bn_apply(
    float* __restrict__ T, const float* __restrict__ stats,
    const float* __restrict__ g, const float* __restrict__ b,
    unsigned short* __restrict__ Thi, unsigned short* __restrict__ Tlo)
{
    int i = blockIdx.x * 256 + threadIdx.x;
    int c = i & 63;
    float mean = stats[c] * (1.f / NN);
    float var  = stats[64 + c] * (1.f / NN) - mean * mean;
    float v = T[i];
    float r = g[c] * (v - mean) * rsqrtf(var + EPSBN) + b[c];
    T[i] = r;
    unsigned short h, l;
    split2(r, h, l);
    Thi[i] = h; Tlo[i] = l;
}

// ---------------------------------------------------------------------------
// TopK pooling + readout + MLP head. One block (128 threads) per graph.
// ---------------------------------------------------------------------------
__global__ __launch_bounds__(128) void pool_mlp(
    const float* __restrict__ Hn, const float* __restrict__ pw,
    const float* __restrict__ W1, const float* __restrict__ b1,
    const float* __restrict__ W2, const float* __restrict__ b2,
    const float* __restrict__ W3, const float* __restrict__ b3,
    float* __restrict__ out)
{
    __shared__ float sh[128][65];
    __shared__ float spw[64];
    __shared__ float sc[128];
    __shared__ float sscale[128];
    __shared__ int   skeep[128];
    __shared__ float rmax[2][64], rsum[2][64];
    __shared__ float srep[128];
    __shared__ float sh1[256];
    __shared__ float sh2[128];
    __shared__ float wred[2];
    const int g = blockIdx.x, t = threadIdx.x;

    for (int i = t; i < 128 * 64; i += 128) sh[i >> 6][i & 63] = Hn[(size_t)g * 128 * 64 + i];
    if (t < 64) spw[t] = pw[t];
    __syncthreads();

    float nw = 0.f;
    #pragma unroll
    for (int i = 0; i < 64; i++) { float w = spw[i]; nw += w * w; }
    float invn = rsqrtf(nw);

    float s = 0.f;
    #pragma unroll
    for (int i = 0; i < 64; i++) s += sh[t][i] * spw[i];
    s *= invn;
    sc[t] = s;
    __syncthreads();

    int rank = 0;
    for (int m = 0; m < 128; m++) {
        float sm = sc[m];
        rank += (sm > s) || (sm == s && m < t);
    }
    skeep[t] = (rank < KTOP);
    sscale[t] = tanhf(s);
    __syncthreads();

    {
        int c = t & 63, half = t >> 6;
        float mxv = -1e30f, sm = 0.f;
        for (int r = half * 64; r < half * 64 + 64; r++) {
            if (skeep[r]) {
                float v = sh[r][c] * sscale[r];
                mxv = fmaxf(mxv, v); sm += v;
            }
        }
        rmax[half][c] = mxv; rsum[half][c] = sm;
    }
    __syncthreads();
    if (t < 64) {
        srep[t] = fmaxf(rmax[0][t], rmax[1][t]);
        srep[64 + t] = (rsum[0][t] + rsum[1][t]) * (1.f / KTOP);
    }
    __syncthreads();

    #pragma unroll
    for (int jj = 0; jj < 2; jj++) {
        int j = t + jj * 128;
        float a = b1[j];
        for (int c2 = 0; c2 < 128; c2++) a += srep[c2] * W1[c2 * 256 + j];
        sh1[j] = fmaxf(a, 0.f);
    }
    __syncthreads();
    {
        float a = b2[t];
        for (int c2 = 0; c2 < 256; c2++) a += sh1[c2] * W2[c2 * 128 + t];
        sh2[t] = fmaxf(a, 0.f);
    }
    __syncthreads();
    float p = sh2[t] * W3[t];
    p += __shfl_xor(p, 1);  p += __shfl_xor(p, 2);  p += __shfl_xor(p, 4);
    p += __shfl_xor(p, 8);  p += __shfl_xor(p, 16); p += __shfl_xor(p, 32);
    if ((t & 63) == 0) wred[t >> 6] = p;
    __syncthreads();
    if (t == 0) out[g] = wred[0] + wred[1] + b3[0];
}

// ---------------------------------------------------------------------------
extern "C" void kernel_launch(void* const* d_in, const int* in_sizes, int n_in,
                              void* d_out, int out_size, void* d_ws, size_t ws_size,
                              hipStream_t stream)
{
    const float* x    = (const float*)d_in[0];
    const int*   ei   = (const int*)  d_in[1];
    const float* ea   = (const float*)d_in[2];
    const int*   srcI = ei;
    const float* Wq1 = (const float*)d_in[4];  const float* bq1 = (const float*)d_in[5];
    const float* Wk1 = (const float*)d_in[6];  const float* bk1 = (const float*)d_in[7];
    const float* Wv1 = (const float*)d_in[8];  const float* bv1 = (const float*)d_in[9];
    const float* We1 = (const float*)d_in[10];
    const float* Ws1 = (const float*)d_in[11]; const float* bs1 = (const float*)d_in[12];
    const float* Wb1 = (const float*)d_in[13];
    const float* t1W = (const float*)d_in[14]; const float* t1b = (const float*)d_in[15];
    const float* g1  = (const float*)d_in[16]; const float* be1 = (const float*)d_in[17];
    const float* Wq2 = (const float*)d_in[18]; const float* bq2 = (const float*)d_in[19];
    const float* Wk2 = (const float*)d_in[20]; const float* bk2 = (const float*)d_in[21];
    const float* Wv2 = (const float*)d_in[22]; const float* bv2 = (const float*)d_in[23];
    const float* We2 = (const float*)d_in[24];
    const float* Ws2 = (const float*)d_in[25]; const float* bs2 = (const float*)d_in[26];
    const float* Wb2 = (const float*)d_in[27];
    const float* t2W = (const float*)d_in[28]; const float* t2b = (const float*)d_in[29];
    const float* g2  = (const float*)d_in[30]; const float* be2 = (const float*)d_in[31];
    const float* pw  = (const float*)d_in[32];
    const float* l1W = (const float*)d_in[33]; const float* l1b = (const float*)d_in[34];
    const float* l2W = (const float*)d_in[35]; const float* l2b = (const float*)d_in[36];
    const float* l3W = (const float*)d_in[37]; const float* l3b = (const float*)d_in[38];

    char* ws = (char*)d_ws;
    unsigned short* C   = (unsigned short*)ws;                     // [NN,1088] bf16
    unsigned short* Hhi = (unsigned short*)(ws + (size_t)NN * NCAT * 2);
    unsigned short* Hlo = Hhi + (size_t)NN * HC;
    float* bT    = (float*)(Hlo + (size_t)NN * HC);                // [NN,64] f32
    unsigned short* bThi = (unsigned short*)(bT + (size_t)NN * 64);
    unsigned short* bTlo = bThi + (size_t)NN * 64;
    unsigned short* Xhi  = bTlo + (size_t)NN * 64;
    unsigned short* Xlo  = Xhi + (size_t)NN * 64;
    float* bcat  = (float*)(Xlo + (size_t)NN * 64);                // [1088]
    float* stats = bcat + NCAT;                                    // [128]
    unsigned short* WThi  = (unsigned short*)(stats + 128);        // [1088][64]
    unsigned short* WTlo  = WThi + (size_t)NCAT * 64;
    unsigned short* tWThi = WTlo + (size_t)NCAT * 64;              // [64][256]
    unsigned short* tWTlo = tWThi + 64 * 256;

    const dim3 blk(256);
    const dim3 gProj(17, 512);

    // ---- layer 1 ----
    split_x<<<NN * 64 / (256 * 8), blk, 0, stream>>>(x, Xhi, Xlo);
    prep<<<18, blk, 0, stream>>>(Wq1, bq1, Wk1, bk1, Wv1, bv1, Ws1, bs1, We1, t1W,
                                 WThi, WTlo, bcat, tWThi, tWTlo);
    proj_mfma<<<gProj, blk, 0, stream>>>(Xhi, Xlo, WThi, WTlo, bcat, C);
    attn_fused<<<NN / 8, blk, 0, stream>>>(C, We1, Wb1, srcI, ea, Hhi, Hlo);
    gemm_t<<<512, blk, 0, stream>>>(Hhi, Hlo, tWThi, tWTlo, t1b, bT);
    zero_stats<<<1, 128, 0, stream>>>(stats);
    bn_stats<<<256, blk, 0, stream>>>(bT, stats);
    bn_apply<<<NN * 64 / 256, blk, 0, stream>>>(bT, stats, g1, be1, bThi, bTlo);

    // ---- layer 2 ----
    prep<<<18, blk, 0, stream>>>(Wq2, bq2, Wk2, bk2, Wv2, bv2, Ws2, bs2, We2, t2W,
                                 WThi, WTlo, bcat, tWThi, tWTlo);
    proj_mfma<<<gProj, blk, 0, stream>>>(bThi, bTlo, WThi, WTlo, bcat, C);
    attn_fused<<<NN / 8, blk, 0, stream>>>(C, We2, Wb2, srcI, ea, Hhi, Hlo);
    gemm_t<<<512, blk, 0, stream>>>(Hhi, Hlo, tWThi, tWTlo, t2b, bT);
    zero_stats<<<1, 128, 0, stream>>>(stats);
    bn_stats<<<256, blk, 0, stream>>>(bT, stats);
    bn_apply<<<NN * 64 / 256, blk, 0, stream>>>(bT, stats, g2, be2, bThi, bTlo);

    // ---- pooling + head ----
    pool_mlp<<<NG, 128, 0, stream>>>(bT, pw, l1W, l1b, l2W, l2b, l3W, l3b,
                                     (float*)d_out);
}